// Round 1
// baseline (9893.883 us; speedup 1.0000x reference)
//
#include <hip/hip_runtime.h>
#include <stdint.h>

#define T_LEN 1024
#define B_SZ  64
#define I_SZ  256
#define H_SZ  512
#define O_SZ  128

// workspace layout (bytes) — unchanged from previous version
#define HB_OFF  0ull                  // 2 bufs * 2 dir * 64 * 512 * 4B = 1048576 (tagged h words)
#define Y_OFF   1048576ull            // 64*1024*1024*2 = 134217728
#define XBF_OFF 135266304ull          // 64*1024*256*2  = 33554432
#define MEMSET_BYTES 1048576ull       // tagged h buffers (memset tag 0 == step-0 expectation)

typedef __attribute__((ext_vector_type(8))) short short8;
typedef __attribute__((ext_vector_type(4))) float f32x4;

__device__ __forceinline__ unsigned short f2bf(float f) {
  unsigned u = __float_as_uint(f);
  u += 0x7fffu + ((u >> 16) & 1u);
  return (unsigned short)(u >> 16);
}
__device__ __forceinline__ ushort4 cvt4(float4 v) {
  ushort4 p;
  p.x = f2bf(v.x); p.y = f2bf(v.y); p.z = f2bf(v.z); p.w = f2bf(v.w);
  return p;
}
__device__ __forceinline__ float sigm(float x) { return 1.0f / (1.0f + __expf(-x)); }
__device__ __forceinline__ float tanh_f(float x) { return 1.0f - 2.0f / (1.0f + __expf(2.0f * x)); }

// ---------------- input fp32 -> bf16 conversion ----------------
__global__ void __launch_bounds__(256) cvt_x(const float* __restrict__ x,
                                             unsigned short* __restrict__ xb) {
  size_t i = ((size_t)blockIdx.x * 256 + threadIdx.x) * 8;
  float4 a = *(const float4*)(x + i);
  float4 b = *(const float4*)(x + i + 4);
  *(ushort4*)(xb + i)     = cvt4(a);
  *(ushort4*)(xb + i + 4) = cvt4(b);
}

// ---------------- persistent bidirectional LSTM scan ----------------
// 64 WGs x 512 thr. Each WG = one direction d, one 32-unit slice, and TWO
// independent batch-group chains (bg pair) interleaved per step: while chain
// A's tagged h store propagates / its poll loads fly, the WG computes chain
// B's sub-step (exchange latency hidden; polls pre-issued one sub-step early
// pass on first check -> contention collapses).
// Slim body: gate-interleaved weight rows so each 4-lane group holds all 4
// gates of one (batch,unit) after an in-wave 4x4 shfl transpose -> cell state
// in registers, NO gbuf/cst LDS, ONE barrier per sub-step; x-part MFMA
// operands loaded fragment-shaped directly from global (no xs staging).
// Exchange skeleton (self-announcing tagged u32 words, agent-scope atomics,
// ping-pong hbuf, memset tag 0) kept verbatim from the proven version.
__global__ void __launch_bounds__(512, 2)
lstm_scan(const unsigned short* __restrict__ xbf,
          const float* __restrict__ WihF, const float* __restrict__ WhhF,
          const float* __restrict__ bihF, const float* __restrict__ bhhF,
          const float* __restrict__ WihB, const float* __restrict__ WhhB,
          const float* __restrict__ bihB, const float* __restrict__ bhhB,
          unsigned char* __restrict__ ws, float* __restrict__ out)
{
  __shared__ unsigned short hs[2][16][520];  // h staging, ping-pong per sub-step

  const int tid  = threadIdx.x;
  const int lane = tid & 63;
  const int wave = tid >> 6;
  const int nl   = lane & 15;          // A-row (batch) for fragments; N-col decode
  const int q16  = lane >> 4;
  const int uu   = nl >> 2;            // unit-within-wave (0..3)
  const int gt   = nl & 3;             // gate owned pre-transpose
  const int mrow = q16 * 4 + gt;       // batch-in-group owned post-transpose

  const int wg   = blockIdx.x;         // 64 WGs
  const int d    = wg >> 5;            // 0 fwd, 1 bwd
  const int pair = (wg >> 4) & 1;      // which bg pair {0,1} or {2,3}
  const int u0   = (wg & 15) * 32;     // unit-slice base
  const int u    = u0 + wave * 4 + uu; // this lane's unit
  const int row  = gt * H_SZ + u;      // gate-interleaved W row

  const float* Wih = d ? WihB : WihF;
  const float* Whh = d ? WhhB : WhhF;
  const float* bih = d ? bihB : bihF;
  const float* bhh = d ? bhhB : bhhF;

  // ---- preload B fragments: wfrag[0..7]=Wih(K=256), [8..23]=Whh(K=512) ----
  short8 wfrag[24];
  {
    const float* wi = Wih + (size_t)row * I_SZ;
    const float* wh = Whh + (size_t)row * H_SZ;
#pragma unroll
    for (int kk = 0; kk < 24; ++kk) {
      const float* src = (kk < 8) ? (wi + kk * 32 + q16 * 8)
                                  : (wh + (kk - 8) * 32 + q16 * 8);
      float4 v0 = ((const float4*)src)[0];
      float4 v1 = ((const float4*)src)[1];
      short8 w;
      w[0] = (short)f2bf(v0.x); w[1] = (short)f2bf(v0.y);
      w[2] = (short)f2bf(v0.z); w[3] = (short)f2bf(v0.w);
      w[4] = (short)f2bf(v1.x); w[5] = (short)f2bf(v1.y);
      w[6] = (short)f2bf(v1.z); w[7] = (short)f2bf(v1.w);
      wfrag[kk] = w;
    }
  }
  const float bias = bih[row] + bhh[row];

  unsigned* hbuf32 = (unsigned*)(ws + HB_OFF);
  unsigned* ybuf32 = (unsigned*)(ws + Y_OFF);

  const int b0h2[2] = { pair * 32, pair * 32 + 16 };
  float cstr[2] = {0.f, 0.f};          // cell state: one register per chain
  f32x4 xacc[2];

  // ---- prologue: x-part MFMAs for s=0, both chains (fragments direct from global) ----
#pragma unroll
  for (int half = 0; half < 2; ++half) {
    const int t0 = d ? (T_LEN - 1) : 0;
    const unsigned short* xr =
        xbf + ((size_t)(b0h2[half] + nl) * T_LEN + t0) * I_SZ + q16 * 8;
    f32x4 xa = {0.f, 0.f, 0.f, 0.f};
#pragma unroll
    for (int kk = 0; kk < 8; ++kk) {
      short8 a = *(const short8*)(xr + kk * 32);
      xa = __builtin_amdgcn_mfma_f32_16x16x32_bf16(a, wfrag[kk], xa, 0, 0, 0);
    }
    xacc[half] = xa;
  }

  // ---- pre-issue tagged h loads for (s=0, chain A): rb=1, tag 0 from memset ----
  unsigned wlo[8], whi[8];
  const unsigned* hb = hbuf32 + (size_t)((1 * 2 + d) * B_SZ + b0h2[0]) * 512;
#pragma unroll
  for (int j = 0; j < 8; ++j) {
    int lin2 = j * 512 + tid, mm = lin2 >> 8, pp = lin2 & 255;
    wlo[j] = __hip_atomic_load(hb + mm * 512 + 2 * pp,     __ATOMIC_RELAXED, __HIP_MEMORY_SCOPE_AGENT);
    whi[j] = __hip_atomic_load(hb + mm * 512 + 2 * pp + 1, __ATOMIC_RELAXED, __HIP_MEMORY_SCOPE_AGENT);
  }

  for (int s = 0; s < T_LEN; ++s) {
    const int t  = d ? (T_LEN - 1 - s) : s;
    const int wb = s & 1;
#pragma unroll
    for (int half = 0; half < 2; ++half) {
      const int b0 = b0h2[half];

      // ---- prefetch x A-fragments for this chain's step s+1 ----
      short8 px[8];
      if (s + 1 < T_LEN) {
        const int tn = d ? (T_LEN - 2 - s) : (s + 1);
        const unsigned short* xr =
            xbf + ((size_t)(b0 + nl) * T_LEN + tn) * I_SZ + q16 * 8;
#pragma unroll
        for (int kk = 0; kk < 8; ++kk) px[kk] = *(const short8*)(xr + kk * 32);
      }

      // ---- poll: all 16 tags must equal s (loads pre-issued last sub-step) ----
      {
        const unsigned tag = (unsigned)s;
        for (;;) {
          unsigned bad = 0;
#pragma unroll
          for (int j = 0; j < 8; ++j)
            bad |= (((wlo[j] ^ tag) | (whi[j] ^ tag)) & 0xffffu) ? (1u << j) : 0u;
          if (!bad) break;
          __builtin_amdgcn_s_sleep(1);
#pragma unroll
          for (int j = 0; j < 8; ++j)
            if (bad & (1u << j)) {
              int lin2 = j * 512 + tid, mm = lin2 >> 8, pp = lin2 & 255;
              wlo[j] = __hip_atomic_load(hb + mm * 512 + 2 * pp,     __ATOMIC_RELAXED, __HIP_MEMORY_SCOPE_AGENT);
              whi[j] = __hip_atomic_load(hb + mm * 512 + 2 * pp + 1, __ATOMIC_RELAXED, __HIP_MEMORY_SCOPE_AGENT);
            }
        }
      }

      // ---- payload -> LDS (pack 2 bf16 per dword) ----
      {
        unsigned* h32 = (unsigned*)&hs[half][0][0];
#pragma unroll
        for (int j = 0; j < 8; ++j) {
          int lin2 = j * 512 + tid, mm = lin2 >> 8, pp = lin2 & 255;
          h32[mm * 260 + pp] = (wlo[j] >> 16) | (whi[j] & 0xffff0000u);
        }
      }
      __syncthreads();  // the ONE barrier of this sub-step

      // ---- h-part MFMAs (dual chains), seeded with precomputed x-part ----
      f32x4 acc0 = xacc[half], acc1 = {0.f, 0.f, 0.f, 0.f};
      {
        const unsigned short* ar = &hs[half][nl][q16 * 8];
#pragma unroll
        for (int kk = 0; kk < 16; kk += 2) {
          short8 a0 = *(const short8*)(ar + kk * 32);
          short8 a1 = *(const short8*)(ar + (kk + 1) * 32);
          acc0 = __builtin_amdgcn_mfma_f32_16x16x32_bf16(a0, wfrag[8 + kk], acc0, 0, 0, 0);
          acc1 = __builtin_amdgcn_mfma_f32_16x16x32_bf16(a1, wfrag[9 + kk], acc1, 0, 0, 0);
        }
        acc0 += acc1;
      }

      // ---- bias + in-wave 4x4 gate transpose (lanes 4u..4u+3) ----
      float a0 = acc0[0] + bias, a1v = acc0[1] + bias;
      float a2 = acc0[2] + bias, a3v = acc0[3] + bias;
      float sh0 = __shfl_xor(a0, 1),  sh1 = __shfl_xor(a1v, 1);
      float sh2 = __shfl_xor(a2, 1),  sh3 = __shfl_xor(a3v, 1);
      float b0v, b1v, b2v, b3v;
      if (lane & 1) { b0v = sh1; b1v = a1v; b2v = sh3; b3v = a3v; }
      else          { b0v = a0;  b1v = sh0; b2v = a2;  b3v = sh2; }
      float uh0 = __shfl_xor(b0v, 2), uh1 = __shfl_xor(b1v, 2);
      float uh2 = __shfl_xor(b2v, 2), uh3 = __shfl_xor(b3v, 2);
      float g_i, g_f, g_g, g_o;
      if (lane & 2) { g_i = uh2; g_f = uh3; g_g = b2v; g_o = b3v; }
      else          { g_i = b0v; g_f = b1v; g_g = uh0; g_o = uh1; }
      // now this lane owns (batch mrow, unit u): i,f,g,o
      g_i = sigm(g_i); g_f = sigm(g_f); g_g = tanh_f(g_g); g_o = sigm(g_o);
      float c = g_f * cstr[half] + g_i * g_g;
      cstr[half] = c;
      float h = g_o * tanh_f(c);
      unsigned hbits = f2bf(h);

      // ---- tagged h store (self-announcing) ----
      __hip_atomic_store(hbuf32 + (size_t)((wb * 2 + d) * B_SZ + b0 + mrow) * 512 + u,
                         (hbits << 16) | (unsigned)(s + 1),
                         __ATOMIC_RELAXED, __HIP_MEMORY_SCOPE_AGENT);
      // ---- y store (pack 2 adjacent units via shfl across lane^4) ----
      unsigned other = __shfl_xor(hbits, 4);
      if (((lane >> 2) & 1) == 0) {
        size_t yi = ((size_t)(b0 + mrow) * T_LEN + t) * 512 + ((d * H_SZ + u) >> 1);
        ybuf32[yi] = hbits | (other << 16);
      }
      if (s == T_LEN - 1) {
        size_t hi = (size_t)(d * B_SZ + b0 + mrow) * H_SZ + u;
        out[8388608ull + hi] = h;            // h_n
        out[8388608ull + 65536ull + hi] = c; // c_n
      }

      // ---- pre-issue next sub-step's tagged loads (other chain / next step) ----
      if (!(s == T_LEN - 1 && half == 1)) {
        const int sn  = half ? (s + 1) : s;
        const int rbn = (sn & 1) ^ 1;
        hb = hbuf32 + (size_t)((rbn * 2 + d) * B_SZ + b0h2[half ^ 1]) * 512;
#pragma unroll
        for (int j = 0; j < 8; ++j) {
          int lin2 = j * 512 + tid, mm = lin2 >> 8, pp = lin2 & 255;
          wlo[j] = __hip_atomic_load(hb + mm * 512 + 2 * pp,     __ATOMIC_RELAXED, __HIP_MEMORY_SCOPE_AGENT);
          whi[j] = __hip_atomic_load(hb + mm * 512 + 2 * pp + 1, __ATOMIC_RELAXED, __HIP_MEMORY_SCOPE_AGENT);
        }
      }

      // ---- x-part MFMAs for this chain's step s+1 (off critical path) ----
      if (s + 1 < T_LEN) {
        f32x4 xa = {0.f, 0.f, 0.f, 0.f};
#pragma unroll
        for (int kk = 0; kk < 8; ++kk)
          xa = __builtin_amdgcn_mfma_f32_16x16x32_bf16(px[kk], wfrag[kk], xa, 0, 0, 0);
        xacc[half] = xa;
      }
    }
  }
}

// ---------------- output projection: out = y @ W_out^T + b_out ----------------
__global__ void __launch_bounds__(256, 1)
proj(const unsigned short* __restrict__ y, const float* __restrict__ Wout,
     const float* __restrict__ bout, float* __restrict__ out)
{
  __shared__ unsigned short ys[128 * 264];
  __shared__ unsigned short wst[128 * 264];

  const int tid  = threadIdx.x;
  const int wave = tid >> 6;
  const int lane = tid & 63;
  const int nl   = lane & 15;
  const int q16  = lane >> 4;
  const int m0   = blockIdx.x * 128;

  f32x4 acc[2][8];
#pragma unroll
  for (int a = 0; a < 2; ++a)
#pragma unroll
    for (int b = 0; b < 8; ++b) acc[a][b] = (f32x4){0.f, 0.f, 0.f, 0.f};

  for (int k0 = 0; k0 < 1024; k0 += 256) {
    {
      int r = tid >> 1, half = tid & 1;
      const uint4* src = (const uint4*)(y + (size_t)(m0 + r) * 1024 + k0 + half * 128);
      uint4* dst = (uint4*)(ys + r * 264 + half * 128);
#pragma unroll
      for (int q = 0; q < 16; ++q) dst[q] = src[q];
    }
    {
      int r = tid >> 1, half = tid & 1;
      const float4* src = (const float4*)(Wout + (size_t)r * 1024 + k0 + half * 128);
      unsigned short* wd = wst + r * 264 + half * 128;
#pragma unroll
      for (int q = 0; q < 32; ++q) *(ushort4*)(wd + q * 4) = cvt4(src[q]);
    }
    __syncthreads();

#pragma unroll
    for (int kk = 0; kk < 8; ++kk) {
      const int ko = kk * 32 + q16 * 8;
      short8 bfr[8];
#pragma unroll
      for (int nt = 0; nt < 8; ++nt)
        bfr[nt] = *(const short8*)(wst + (nt * 16 + nl) * 264 + ko);
#pragma unroll
      for (int mtt = 0; mtt < 2; ++mtt) {
        short8 a = *(const short8*)(ys + ((wave * 2 + mtt) * 16 + nl) * 264 + ko);
#pragma unroll
        for (int nt = 0; nt < 8; ++nt)
          acc[mtt][nt] = __builtin_amdgcn_mfma_f32_16x16x32_bf16(a, bfr[nt], acc[mtt][nt], 0, 0, 0);
      }
    }
    __syncthreads();
  }

#pragma unroll
  for (int mtt = 0; mtt < 2; ++mtt) {
#pragma unroll
    for (int nt = 0; nt < 8; ++nt) {
      int col = nt * 16 + nl;
      float bo = bout[col];
      int rowb = m0 + (wave * 2 + mtt) * 16 + q16 * 4;
#pragma unroll
      for (int r = 0; r < 4; ++r)
        out[(size_t)(rowb + r) * O_SZ + col] = acc[mtt][nt][r] + bo;
    }
  }
}

extern "C" void kernel_launch(void* const* d_in, const int* in_sizes, int n_in,
                              void* d_out, int out_size, void* d_ws, size_t ws_size,
                              hipStream_t stream) {
  const float* x    = (const float*)d_in[0];
  const float* WihF = (const float*)d_in[1];
  const float* WhhF = (const float*)d_in[2];
  const float* bihF = (const float*)d_in[3];
  const float* bhhF = (const float*)d_in[4];
  const float* WihB = (const float*)d_in[5];
  const float* WhhB = (const float*)d_in[6];
  const float* bihB = (const float*)d_in[7];
  const float* bhhB = (const float*)d_in[8];
  const float* Wout = (const float*)d_in[9];
  const float* bout = (const float*)d_in[10];
  float* out = (float*)d_out;
  unsigned char* ws = (unsigned char*)d_ws;

  hipMemsetAsync(ws, 0, (size_t)MEMSET_BYTES, stream);
  cvt_x<<<8192, 256, 0, stream>>>(x, (unsigned short*)(ws + XBF_OFF));
  lstm_scan<<<64, 512, 0, stream>>>((const unsigned short*)(ws + XBF_OFF),
                                    WihF, WhhF, bihF, bhhF,
                                    WihB, WhhB, bihB, bhhB,
                                    ws, out);
  proj<<<512, 256, 0, stream>>>((const unsigned short*)(ws + Y_OFF), Wout, bout, out);
}

// Round 3
// 4380.725 us; speedup vs baseline: 2.2585x; 2.2585x over previous
//
#include <hip/hip_runtime.h>
#include <stdint.h>

#define T_LEN 1024
#define B_SZ  64
#define I_SZ  256
#define H_SZ  512
#define O_SZ  128

// workspace layout (bytes)
#define HB_OFF   0ull                 // pair-packed h: 2 bufs*2 dir*64*256 u32 = 256KB
#define SENT_OFF 786432ull            // sentinels: [buf][chain][slice] = 2*8*16 u32 = 1KB
#define Y_OFF    1048576ull           // 64*1024*1024*2 = 134217728
#define XBF_OFF  135266304ull         // 64*1024*256*2  = 33554432
#define MEMSET_BYTES 1048576ull       // covers h region + sentinels (zero == step-0 expectation)

typedef __attribute__((ext_vector_type(8))) short short8;
typedef __attribute__((ext_vector_type(4))) float f32x4;

__device__ __forceinline__ unsigned short f2bf(float f) {
  unsigned u = __float_as_uint(f);
  u += 0x7fffu + ((u >> 16) & 1u);
  return (unsigned short)(u >> 16);
}
__device__ __forceinline__ ushort4 cvt4(float4 v) {
  ushort4 p;
  p.x = f2bf(v.x); p.y = f2bf(v.y); p.z = f2bf(v.z); p.w = f2bf(v.w);
  return p;
}
__device__ __forceinline__ float sigm(float x) { return 1.0f / (1.0f + __expf(-x)); }
__device__ __forceinline__ float tanh_f(float x) { return 1.0f - 2.0f / (1.0f + __expf(2.0f * x)); }

// ---------------- input fp32 -> bf16 conversion ----------------
__global__ void __launch_bounds__(256) cvt_x(const float* __restrict__ x,
                                             unsigned short* __restrict__ xb) {
  size_t i = ((size_t)blockIdx.x * 256 + threadIdx.x) * 8;
  float4 a = *(const float4*)(x + i);
  float4 b = *(const float4*)(x + i + 4);
  *(ushort4*)(xb + i)     = cvt4(a);
  *(ushort4*)(xb + i + 4) = cvt4(b);
}

// ---------------- persistent bidirectional LSTM scan ----------------
// 128 WGs x 512 thr, one chain-slice per WG (R0 mapping: d=wg>>6, bg=(wg>>4)&3,
// slice=wg&15). All cross-WG traffic stays in the PROVEN sc1/MALL domain.
// Exchange = sentinel-release protocol:
//   producer: pair-packed h stores (relaxed sc1, tag-free) -> explicit
//             s_waitcnt vmcnt(0) + __syncthreads (ack = release point for sc1
//             stores) -> tid0 stores one sentinel word = s+1 (relaxed sc1).
//   consumer: tid0 polls the chain's 16 sentinels (64B/round, not 32KB) until
//             all == s -> barrier -> ONE bulk load of the 4K pair-words
//             (visible by release ordering; no re-poll).
// Ping-pong h+sentinel buffers; memset-zero bootstraps step 0 (h=0, sent=0).
// Overwrite-after-read safety is transitive through the sentinel chain, same
// induction as R0. Body = R1's harness-verified slim step (gate-interleaved
// weight rows, in-wave 4x4 gate transpose, register cell state, one compute
// barrier, x operands loaded fragment-shaped from global).
__global__ void __launch_bounds__(512, 1)
lstm_scan(const unsigned short* __restrict__ xbf,
          const float* __restrict__ WihF, const float* __restrict__ WhhF,
          const float* __restrict__ bihF, const float* __restrict__ bhhF,
          const float* __restrict__ WihB, const float* __restrict__ WhhB,
          const float* __restrict__ bihB, const float* __restrict__ bhhB,
          unsigned char* __restrict__ ws, float* __restrict__ out)
{
  __shared__ unsigned hsL[16][260];    // h staging, pair-packed (16 batch x 256 pairs)

  const int tid  = threadIdx.x;
  const int lane = tid & 63;
  const int wave = tid >> 6;
  const int nl   = lane & 15;          // A-row (batch); B-frag N index
  const int q16  = lane >> 4;
  const int uu   = nl >> 2;            // unit-within-wave (0..3)
  const int gt   = nl & 3;             // gate owned pre-transpose
  const int mrow = q16 * 4 + gt;       // batch-in-group owned post-transpose

  const int wg    = blockIdx.x;        // 128 WGs
  const int d     = wg >> 6;           // 0 fwd, 1 bwd
  const int bg    = (wg >> 4) & 3;     // batch-group
  const int slice = wg & 15;           // unit-slice
  const int b0    = bg * 16;
  const int u0    = slice * 32;
  const int u     = u0 + wave * 4 + uu;
  const int row   = gt * H_SZ + u;     // gate-interleaved W row
  const int chain = d * 4 + bg;        // 0..7

  const float* Wih = d ? WihB : WihF;
  const float* Whh = d ? WhhB : WhhF;
  const float* bih = d ? bihB : bihF;
  const float* bhh = d ? bhhB : bhhF;

  // ---- preload B fragments: wfrag[0..7]=Wih(K=256), [8..23]=Whh(K=512) ----
  short8 wfrag[24];
  {
    const float* wi = Wih + (size_t)row * I_SZ;
    const float* wh = Whh + (size_t)row * H_SZ;
#pragma unroll
    for (int kk = 0; kk < 24; ++kk) {
      const float* src = (kk < 8) ? (wi + kk * 32 + q16 * 8)
                                  : (wh + (kk - 8) * 32 + q16 * 8);
      float4 v0 = ((const float4*)src)[0];
      float4 v1 = ((const float4*)src)[1];
      short8 w;
      w[0] = (short)f2bf(v0.x); w[1] = (short)f2bf(v0.y);
      w[2] = (short)f2bf(v0.z); w[3] = (short)f2bf(v0.w);
      w[4] = (short)f2bf(v1.x); w[5] = (short)f2bf(v1.y);
      w[6] = (short)f2bf(v1.z); w[7] = (short)f2bf(v1.w);
      wfrag[kk] = w;
    }
  }
  const float bias = bih[row] + bhh[row];

  unsigned* hbuf32 = (unsigned*)(ws + HB_OFF);   // pair-packed h
  unsigned* sent   = (unsigned*)(ws + SENT_OFF); // sentinels
  unsigned* ybuf32 = (unsigned*)(ws + Y_OFF);

  float cstr = 0.0f;
  f32x4 xacc;

  // ---- prologue: x-part MFMAs for s=0 (fragments direct from global) ----
  {
    const int t0 = d ? (T_LEN - 1) : 0;
    const unsigned short* xr =
        xbf + ((size_t)(b0 + nl) * T_LEN + t0) * I_SZ + q16 * 8;
    f32x4 xa = {0.f, 0.f, 0.f, 0.f};
#pragma unroll
    for (int kk = 0; kk < 8; ++kk) {
      short8 a = *(const short8*)(xr + kk * 32);
      xa = __builtin_amdgcn_mfma_f32_16x16x32_bf16(a, wfrag[kk], xa, 0, 0, 0);
    }
    xacc = xa;
  }

  for (int s = 0; s < T_LEN; ++s) {
    const int t  = d ? (T_LEN - 1 - s) : s;
    const int rb = (s & 1) ^ 1, wb = s & 1;

    // ---- poll sentinels (tid0 only): all 16 slices announced step s ----
    if (tid == 0) {
      const unsigned* sp = sent + (rb * 8 + chain) * 16;
      for (;;) {
        unsigned bad = 0;
#pragma unroll
        for (int k = 0; k < 16; ++k)
          bad |= (__hip_atomic_load(sp + k, __ATOMIC_RELAXED,
                                    __HIP_MEMORY_SCOPE_AGENT) != (unsigned)s);
        if (!bad) break;
      }
    }
    __syncthreads();  // B3: sentinel observed -> bulk loads may issue

    // ---- bulk h load: 8 pair-words/thread, one shot, no re-poll ----
    const unsigned* hb = hbuf32 + (size_t)((rb * 2 + d) * B_SZ + b0) * 256;
    unsigned wv[8];
#pragma unroll
    for (int j = 0; j < 8; ++j)
      wv[j] = __hip_atomic_load(hb + j * 512 + tid, __ATOMIC_RELAXED,
                                __HIP_MEMORY_SCOPE_AGENT);

    // ---- stage to LDS ----
#pragma unroll
    for (int j = 0; j < 8; ++j) {
      int lin = j * 512 + tid;
      hsL[lin >> 8][lin & 255] = wv[j];
    }
    __syncthreads();  // B1: staging visible

    // ---- prefetch x A-fragments for s+1 (latency hides under MFMA phase) ----
    short8 px[8];
    if (s + 1 < T_LEN) {
      const int tn = d ? (T_LEN - 2 - s) : (s + 1);
      const unsigned short* xr =
          xbf + ((size_t)(b0 + nl) * T_LEN + tn) * I_SZ + q16 * 8;
#pragma unroll
      for (int kk = 0; kk < 8; ++kk) px[kk] = *(const short8*)(xr + kk * 32);
    }

    // ---- h-part MFMAs (dual chains), seeded with precomputed x-part ----
    f32x4 acc0 = xacc, acc1 = {0.f, 0.f, 0.f, 0.f};
    {
      const unsigned short* ar = (const unsigned short*)&hsL[nl][0] + q16 * 8;
#pragma unroll
      for (int kk = 0; kk < 16; kk += 2) {
        short8 a0v = *(const short8*)(ar + kk * 32);
        short8 a1v = *(const short8*)(ar + (kk + 1) * 32);
        acc0 = __builtin_amdgcn_mfma_f32_16x16x32_bf16(a0v, wfrag[8 + kk], acc0, 0, 0, 0);
        acc1 = __builtin_amdgcn_mfma_f32_16x16x32_bf16(a1v, wfrag[9 + kk], acc1, 0, 0, 0);
      }
      acc0 += acc1;
    }

    // ---- bias + in-wave 4x4 gate transpose (lanes 4u..4u+3) ----
    float a0f = acc0[0] + bias, a1f = acc0[1] + bias;
    float a2f = acc0[2] + bias, a3f = acc0[3] + bias;
    float sh0 = __shfl_xor(a0f, 1), sh1 = __shfl_xor(a1f, 1);
    float sh2 = __shfl_xor(a2f, 1), sh3 = __shfl_xor(a3f, 1);
    float b0v, b1v, b2v, b3v;
    if (lane & 1) { b0v = sh1; b1v = a1f; b2v = sh3; b3v = a3f; }
    else          { b0v = a0f; b1v = sh0; b2v = a2f; b3v = sh2; }
    float uh0 = __shfl_xor(b0v, 2), uh1 = __shfl_xor(b1v, 2);
    float uh2 = __shfl_xor(b2v, 2), uh3 = __shfl_xor(b3v, 2);
    float g_i, g_f, g_g, g_o;
    if (lane & 2) { g_i = uh2; g_f = uh3; g_g = b2v; g_o = b3v; }
    else          { g_i = b0v; g_f = b1v; g_g = uh0; g_o = uh1; }
    g_i = sigm(g_i); g_f = sigm(g_f); g_g = tanh_f(g_g); g_o = sigm(g_o);
    float cc = g_f * cstr + g_i * g_g;
    cstr = cc;
    float h = g_o * tanh_f(cc);
    unsigned hbits = f2bf(h);

    // ---- pair-packed h store (tag-free, relaxed sc1) ----
    unsigned other = __shfl_xor(hbits, 4);
    unsigned pairw = hbits | (other << 16);   // low = even unit u, high = u+1
    if (((lane >> 2) & 1) == 0)
      __hip_atomic_store(hbuf32 + (size_t)((wb * 2 + d) * B_SZ + b0 + mrow) * 256 + (u >> 1),
                         pairw, __ATOMIC_RELAXED, __HIP_MEMORY_SCOPE_AGENT);

    // ---- release: drain store acks (MALL visibility), then WG-wide barrier ----
    asm volatile("s_waitcnt vmcnt(0)" ::: "memory");
    __syncthreads();  // B2: all 512 threads' h stores (and px loads) complete

    // ---- sentinel announce (one word per slice) ----
    if (tid == 0)
      __hip_atomic_store(sent + (wb * 8 + chain) * 16 + slice, (unsigned)(s + 1),
                         __ATOMIC_RELAXED, __HIP_MEMORY_SCOPE_AGENT);

    // ---- y store (plain; off the exchange path) ----
    if (((lane >> 2) & 1) == 0) {
      size_t yi = ((size_t)(b0 + mrow) * T_LEN + t) * 512 + ((d * H_SZ + u) >> 1);
      ybuf32[yi] = pairw;
    }
    if (s == T_LEN - 1) {
      size_t hi = (size_t)(d * B_SZ + b0 + mrow) * H_SZ + u;
      out[8388608ull + hi] = h;             // h_n
      out[8388608ull + 65536ull + hi] = cc; // c_n
    }

    // ---- x-part MFMAs for step s+1 (overlaps sentinel flight) ----
    if (s + 1 < T_LEN) {
      f32x4 xa = {0.f, 0.f, 0.f, 0.f};
#pragma unroll
      for (int kk = 0; kk < 8; ++kk)
        xa = __builtin_amdgcn_mfma_f32_16x16x32_bf16(px[kk], wfrag[kk], xa, 0, 0, 0);
      xacc = xa;
    }
  }
}

// ---------------- output projection: out = y @ W_out^T + b_out ----------------
__global__ void __launch_bounds__(256, 1)
proj(const unsigned short* __restrict__ y, const float* __restrict__ Wout,
     const float* __restrict__ bout, float* __restrict__ out)
{
  __shared__ unsigned short ys[128 * 264];
  __shared__ unsigned short wst[128 * 264];

  const int tid  = threadIdx.x;
  const int wave = tid >> 6;
  const int lane = tid & 63;
  const int nl   = lane & 15;
  const int q16  = lane >> 4;
  const int m0   = blockIdx.x * 128;

  f32x4 acc[2][8];
#pragma unroll
  for (int a = 0; a < 2; ++a)
#pragma unroll
    for (int b = 0; b < 8; ++b) acc[a][b] = (f32x4){0.f, 0.f, 0.f, 0.f};

  for (int k0 = 0; k0 < 1024; k0 += 256) {
    {
      int r = tid >> 1, half = tid & 1;
      const uint4* src = (const uint4*)(y + (size_t)(m0 + r) * 1024 + k0 + half * 128);
      uint4* dst = (uint4*)(ys + r * 264 + half * 128);
#pragma unroll
      for (int q = 0; q < 16; ++q) dst[q] = src[q];
    }
    {
      int r = tid >> 1, half = tid & 1;
      const float4* src = (const float4*)(Wout + (size_t)r * 1024 + k0 + half * 128);
      unsigned short* wd = wst + r * 264 + half * 128;
#pragma unroll
      for (int q = 0; q < 32; ++q) *(ushort4*)(wd + q * 4) = cvt4(src[q]);
    }
    __syncthreads();

#pragma unroll
    for (int kk = 0; kk < 8; ++kk) {
      const int ko = kk * 32 + q16 * 8;
      short8 bfr[8];
#pragma unroll
      for (int nt = 0; nt < 8; ++nt)
        bfr[nt] = *(const short8*)(wst + (nt * 16 + nl) * 264 + ko);
#pragma unroll
      for (int mtt = 0; mtt < 2; ++mtt) {
        short8 a = *(const short8*)(ys + ((wave * 2 + mtt) * 16 + nl) * 264 + ko);
#pragma unroll
        for (int nt = 0; nt < 8; ++nt)
          acc[mtt][nt] = __builtin_amdgcn_mfma_f32_16x16x32_bf16(a, bfr[nt], acc[mtt][nt], 0, 0, 0);
      }
    }
    __syncthreads();
  }

#pragma unroll
  for (int mtt = 0; mtt < 2; ++mtt) {
#pragma unroll
    for (int nt = 0; nt < 8; ++nt) {
      int col = nt * 16 + nl;
      float bo = bout[col];
      int rowb = m0 + (wave * 2 + mtt) * 16 + q16 * 4;
#pragma unroll
      for (int r = 0; r < 4; ++r)
        out[(size_t)(rowb + r) * O_SZ + col] = acc[mtt][nt][r] + bo;
    }
  }
}

extern "C" void kernel_launch(void* const* d_in, const int* in_sizes, int n_in,
                              void* d_out, int out_size, void* d_ws, size_t ws_size,
                              hipStream_t stream) {
  const float* x    = (const float*)d_in[0];
  const float* WihF = (const float*)d_in[1];
  const float* WhhF = (const float*)d_in[2];
  const float* bihF = (const float*)d_in[3];
  const float* bhhF = (const float*)d_in[4];
  const float* WihB = (const float*)d_in[5];
  const float* WhhB = (const float*)d_in[6];
  const float* bihB = (const float*)d_in[7];
  const float* bhhB = (const float*)d_in[8];
  const float* Wout = (const float*)d_in[9];
  const float* bout = (const float*)d_in[10];
  float* out = (float*)d_out;
  unsigned char* ws = (unsigned char*)d_ws;

  hipMemsetAsync(ws, 0, (size_t)MEMSET_BYTES, stream);
  cvt_x<<<8192, 256, 0, stream>>>(x, (unsigned short*)(ws + XBF_OFF));
  lstm_scan<<<128, 512, 0, stream>>>((const unsigned short*)(ws + XBF_OFF),
                                     WihF, WhhF, bihF, bhhF,
                                     WihB, WhhB, bihB, bhhB,
                                     ws, out);
  proj<<<512, 256, 0, stream>>>((const unsigned short*)(ws + Y_OFF), Wout, bout, out);
}